// Round 5
// baseline (166.515 us; speedup 1.0000x reference)
//
#include <hip/hip_runtime.h>

#define N_ROWS 4096
#define D_DIM  512
#define C_ROWS 8192
#define MT (N_ROWS / 64)        // 64 M-tiles
#define NT (C_ROWS / 64)        // 128 N-tiles
#define NWAVE (MT * NT)         // 8192 waves, 2048 blocks
#define NBLK2 NWAVE             // per-wave partials

typedef __attribute__((ext_vector_type(8))) short bfrag8;   // 8 bf16
typedef __attribute__((ext_vector_type(4))) float f32x4;    // MFMA acc
typedef __attribute__((ext_vector_type(8))) unsigned short ushort8;

__device__ __forceinline__ unsigned short f2bf(float f) {
    unsigned int u = __float_as_uint(f);
    unsigned int r = (u + 0x7fffu + ((u >> 16) & 1u)) >> 16;   // RNE
    return (unsigned short)r;
}
__device__ __forceinline__ float bf2f(unsigned short h) {
    return __uint_as_float(((unsigned int)h) << 16);
}

// ---------------- l2-normalize rows, fp32 -> bf16 ----------------
__global__ __launch_bounds__(256) void normalize_kernel(
        const float* __restrict__ src, unsigned short* __restrict__ dst, int rows) {
    const int w    = threadIdx.x >> 6;
    const int lane = threadIdx.x & 63;
    const int row  = blockIdx.x * 4 + w;
    if (row >= rows) return;

    const float* r = src + (size_t)row * D_DIM + lane * 8;
    float4 v0 = *(const float4*)(r);
    float4 v1 = *(const float4*)(r + 4);
    float ss = v0.x*v0.x + v0.y*v0.y + v0.z*v0.z + v0.w*v0.w
             + v1.x*v1.x + v1.y*v1.y + v1.z*v1.z + v1.w*v1.w;
    #pragma unroll
    for (int off = 32; off; off >>= 1) ss += __shfl_xor(ss, off);
    const float nrm = sqrtf(ss);
    const float sc  = 1.0f / fmaxf(nrm, 1e-12f);

    ushort8 pk;
    pk[0] = f2bf(v0.x * sc); pk[1] = f2bf(v0.y * sc);
    pk[2] = f2bf(v0.z * sc); pk[3] = f2bf(v0.w * sc);
    pk[4] = f2bf(v1.x * sc); pk[5] = f2bf(v1.y * sc);
    pk[6] = f2bf(v1.z * sc); pk[7] = f2bf(v1.w * sc);
    *(ushort8*)(dst + (size_t)row * D_DIM + lane * 8) = pk;
}

// ---------------- pos_dot[i] = fN[i] . cN[labels[i]] ----------------
__global__ __launch_bounds__(256) void posdot_kernel(
        const unsigned short* __restrict__ fN, const unsigned short* __restrict__ cN,
        const int* __restrict__ labels, float* __restrict__ pos) {
    const int w    = threadIdx.x >> 6;
    const int lane = threadIdx.x & 63;
    const int i    = blockIdx.x * 4 + w;
    const int lab  = labels[i];

    ushort8 a = *(const ushort8*)(fN + (size_t)i   * D_DIM + lane * 8);
    ushort8 b = *(const ushort8*)(cN + (size_t)lab * D_DIM + lane * 8);
    float s = 0.0f;
    #pragma unroll
    for (int t = 0; t < 8; ++t) s += bf2f(a[t]) * bf2f(b[t]);
    #pragma unroll
    for (int off = 32; off; off >>= 1) s += __shfl_xor(s, off);
    if (lane == 0) pos[i] = s;
}

// ---------------- fused GEMM + masked softplus reduction ----------------
// Wave-private register GEMM: each wave owns a 64x64 output tile.
// A/B fragments loaded DIRECTLY from global (per-lane 16B dwordx4 -- the
// 16x16x32 fragment layout is 16 contiguous bytes per lane). Zero LDS,
// zero barriers: pure TLP/ILP latency hiding. 2-stage register pipeline.
// Block = 4 waves sharing one A-panel (L1 reuse); XCD swizzle gives each
// XCD a 1 MB B-stripe (L2-resident):  id -> xcd=id&7, local=id>>3,
// mT=local>>2, ng=(local&3)+xcd*4, nT=ng*4+w.   (2048 = 8*64*4, bijective)
__global__ __launch_bounds__(256) void fused_loss_kernel(
        const unsigned short* __restrict__ fN, const unsigned short* __restrict__ cN,
        const int* __restrict__ labels, const float* __restrict__ pos,
        float* __restrict__ partialL, unsigned int* __restrict__ partialC) {
    const int w    = threadIdx.x >> 6;
    const int lane = threadIdx.x & 63;
    const int lr   = lane & 15;
    const int kq   = lane >> 4;

    const int id    = blockIdx.x;          // 0..2047
    const int xcd   = id & 7;
    const int local = id >> 3;             // 0..255
    const int mT    = local >> 2;          // 0..63
    const int ng    = (local & 3) + xcd * 4;   // 0..31
    const int nT    = ng * 4 + w;          // 0..127
    const int rowBase = mT * 64;
    const int colBase = nT * 64;

    // per-lane fragment base pointers (frag m: +m*16 rows; k-step kt: +kt*32)
    const unsigned short* aP = fN + (size_t)(rowBase + lr) * D_DIM + kq * 8;
    const unsigned short* bP = cN + (size_t)(colBase + lr) * D_DIM + kq * 8;

#define LOAD4(dst, P, kt)                                                   \
    do {                                                                    \
        dst[0] = *(const bfrag8*)((P) + (kt) * 32 + 0 * 16 * D_DIM);        \
        dst[1] = *(const bfrag8*)((P) + (kt) * 32 + 1 * 16 * D_DIM);        \
        dst[2] = *(const bfrag8*)((P) + (kt) * 32 + 2 * 16 * D_DIM);        \
        dst[3] = *(const bfrag8*)((P) + (kt) * 32 + 3 * 16 * D_DIM);        \
    } while (0)

#define MFMA16(A, B)                                                        \
    do {                                                                    \
        _Pragma("unroll")                                                   \
        for (int m = 0; m < 4; ++m)                                         \
            _Pragma("unroll")                                               \
            for (int n = 0; n < 4; ++n)                                     \
                acc[m][n] = __builtin_amdgcn_mfma_f32_16x16x32_bf16(        \
                                A[m], B[n], acc[m][n], 0, 0, 0);            \
    } while (0)

    f32x4 acc[4][4] = {};
    bfrag8 a0[4], b0[4], a1[4], b1[4];

    // 2-stage register pipeline over 16 K-steps (K=512, BK=32)
    LOAD4(a0, aP, 0); LOAD4(b0, bP, 0);
    #pragma unroll
    for (int kt = 0; kt < 16; kt += 2) {
        LOAD4(a1, aP, kt + 1); LOAD4(b1, bP, kt + 1);
        MFMA16(a0, b0);
        if (kt + 2 < 16) { LOAD4(a0, aP, kt + 2); LOAD4(b0, bP, kt + 2); }
        MFMA16(a1, b1);
    }
#undef LOAD4
#undef MFMA16

    // ---- epilogue: x = S_ij - pos[i]; mask j != label[i]; softplus; sum ----
    float lsum = 0.0f;
    unsigned cnt = 0;
    #pragma unroll
    for (int m = 0; m < 4; ++m) {
        #pragma unroll
        for (int j = 0; j < 4; ++j) {
            const int gi = rowBase + m * 16 + kq * 4 + j;
            const float p = pos[gi];
            const int lab = labels[gi];
            #pragma unroll
            for (int n = 0; n < 4; ++n) {
                const int gj = colBase + n * 16 + lr;
                const float x = acc[m][n][j] - p;
                if (gj != lab) {
                    const float l = __logf(1.0f + __expf(x));   // softplus
                    if (l > 0.0f) { lsum += l; cnt++; }
                }
            }
        }
    }
    #pragma unroll
    for (int off = 32; off; off >>= 1) {
        lsum += __shfl_xor(lsum, off);
        cnt  += __shfl_xor(cnt,  off);
    }
    if (lane == 0) {
        partialL[(id << 2) | w] = lsum;
        partialC[(id << 2) | w] = cnt;
    }
}

// ---------------- finalize: reduce 8192 per-wave partials ----------------
__global__ __launch_bounds__(256) void finalize_kernel(
        const float* __restrict__ partialL, const unsigned int* __restrict__ partialC,
        float* __restrict__ out) {
    __shared__ float    s_sum[4];
    __shared__ unsigned s_cnt[4];
    const int w    = threadIdx.x >> 6;
    const int lane = threadIdx.x & 63;

    float s = 0.0f; unsigned c = 0;
    for (int i = threadIdx.x; i < NBLK2; i += 256) { s += partialL[i]; c += partialC[i]; }
    #pragma unroll
    for (int off = 32; off; off >>= 1) {
        s += __shfl_xor(s, off);
        c += __shfl_xor(c, off);
    }
    if (lane == 0) { s_sum[w] = s; s_cnt[w] = c; }
    __syncthreads();
    if (threadIdx.x == 0) {
        const float    l = s_sum[0] + s_sum[1] + s_sum[2] + s_sum[3];
        const unsigned n = s_cnt[0] + s_cnt[1] + s_cnt[2] + s_cnt[3];
        out[0] = (n > 0u) ? l / (float)n : l;
    }
}

extern "C" void kernel_launch(void* const* d_in, const int* in_sizes, int n_in,
                              void* d_out, int out_size, void* d_ws, size_t ws_size,
                              hipStream_t stream) {
    const float* features = (const float*)d_in[0];   // [4096, 512]
    const float* centers  = (const float*)d_in[1];   // [8192, 512]
    const int*   labels   = (const int*)d_in[2];     // [4096]
    float* out = (float*)d_out;

    char* ws = (char*)d_ws;
    unsigned short* fN  = (unsigned short*)ws;                        // 4 MB
    unsigned short* cN  = (unsigned short*)(ws + (4u << 20));         // 8 MB
    float*          pos = (float*)(ws + (12u << 20));                 // 16 KB
    float*          partialL = (float*)(ws + (12u << 20) + (1u << 16));          // 32 KB
    unsigned int*   partialC = (unsigned int*)(ws + (12u << 20) + (1u << 16) + (1u << 15)); // 32 KB

    normalize_kernel<<<N_ROWS / 4, 256, 0, stream>>>(features, fN, N_ROWS);
    normalize_kernel<<<C_ROWS / 4, 256, 0, stream>>>(centers,  cN, C_ROWS);
    posdot_kernel<<<N_ROWS / 4, 256, 0, stream>>>(fN, cN, labels, pos);

    fused_loss_kernel<<<NWAVE / 4, 256, 0, stream>>>(fN, cN, labels, pos, partialL, partialC);

    finalize_kernel<<<1, 256, 0, stream>>>(partialL, partialC, out);
}

// Round 6
// 86.704 us; speedup vs baseline: 1.9205x; 1.9205x over previous
//
#include <hip/hip_runtime.h>

#define N_ROWS 4096
#define D_DIM  512
#define C_ROWS 8192
#define BM 256
#define BN 128
#define BK 32
#define NKT (D_DIM / BK)            // 16 K-tiles
#define GX (C_ROWS / BN)            // 64
#define GY (N_ROWS / BM)            // 16
#define NBLKG (GX * GY)             // 1024 blocks
#define NPART (NBLKG * 4)           // per-wave partials

typedef __attribute__((ext_vector_type(8))) short bfrag8;   // 8 bf16
typedef __attribute__((ext_vector_type(4))) float f32x4;    // MFMA acc
typedef __attribute__((ext_vector_type(8))) unsigned short ushort8;

#define AS1 __attribute__((address_space(1)))
#define AS3 __attribute__((address_space(3)))

__device__ __forceinline__ void gload_lds16(const void* g, void* l) {
    __builtin_amdgcn_global_load_lds((const AS1 unsigned int*)g,
                                     (AS3 unsigned int*)l, 16, 0, 0);
}

__device__ __forceinline__ unsigned short f2bf(float f) {
    unsigned int u = __float_as_uint(f);
    unsigned int r = (u + 0x7fffu + ((u >> 16) & 1u)) >> 16;   // RNE
    return (unsigned short)r;
}
__device__ __forceinline__ float bf2f(unsigned short h) {
    return __uint_as_float(((unsigned int)h) << 16);
}

// ---------------- l2-normalize rows, fp32 -> bf16 ----------------
__global__ __launch_bounds__(256) void normalize_kernel(
        const float* __restrict__ src, unsigned short* __restrict__ dst, int rows) {
    const int w    = threadIdx.x >> 6;
    const int lane = threadIdx.x & 63;
    const int row  = blockIdx.x * 4 + w;
    if (row >= rows) return;

    const float* r = src + (size_t)row * D_DIM + lane * 8;
    float4 v0 = *(const float4*)(r);
    float4 v1 = *(const float4*)(r + 4);
    float ss = v0.x*v0.x + v0.y*v0.y + v0.z*v0.z + v0.w*v0.w
             + v1.x*v1.x + v1.y*v1.y + v1.z*v1.z + v1.w*v1.w;
    #pragma unroll
    for (int off = 32; off; off >>= 1) ss += __shfl_xor(ss, off);
    const float nrm = sqrtf(ss);
    const float sc  = 1.0f / fmaxf(nrm, 1e-12f);

    ushort8 pk;
    pk[0] = f2bf(v0.x * sc); pk[1] = f2bf(v0.y * sc);
    pk[2] = f2bf(v0.z * sc); pk[3] = f2bf(v0.w * sc);
    pk[4] = f2bf(v1.x * sc); pk[5] = f2bf(v1.y * sc);
    pk[6] = f2bf(v1.z * sc); pk[7] = f2bf(v1.w * sc);
    *(ushort8*)(dst + (size_t)row * D_DIM + lane * 8) = pk;
}

// ---------------- pos_dot[i] = fN[i] . cN[labels[i]] ----------------
__global__ __launch_bounds__(256) void posdot_kernel(
        const unsigned short* __restrict__ fN, const unsigned short* __restrict__ cN,
        const int* __restrict__ labels, float* __restrict__ pos) {
    const int w    = threadIdx.x >> 6;
    const int lane = threadIdx.x & 63;
    const int i    = blockIdx.x * 4 + w;
    const int lab  = labels[i];

    ushort8 a = *(const ushort8*)(fN + (size_t)i   * D_DIM + lane * 8);
    ushort8 b = *(const ushort8*)(cN + (size_t)lab * D_DIM + lane * 8);
    float s = 0.0f;
    #pragma unroll
    for (int t = 0; t < 8; ++t) s += bf2f(a[t]) * bf2f(b[t]);
    #pragma unroll
    for (int off = 32; off; off >>= 1) s += __shfl_xor(s, off);
    if (lane == 0) pos[i] = s;
}

// ---------------- fused GEMM + masked softplus reduction ----------------
// 256x128 tile, BK=32, 4 waves (2M x 2N, wave tile 128x64), TRIPLE-buffered
// LDS (72 KB -> 2 independent blocks/CU for stall overlap). Per K-tile:
// one counted vmcnt(6) (2-tile lookahead), one barrier, stage AFTER barrier,
// 12 ds_read_b128, lgkmcnt(0)+sched_barrier, setprio around 32 MFMA.
// BK=32 swizzle: LDS 16B-seg s of row r holds global seg s ^ ((r>>1)&3)
// -> 2-way (free) read pattern; write side pre-swizzles the global source.
__global__ __launch_bounds__(256, 2) void fused_loss_kernel(
        const unsigned short* __restrict__ fN, const unsigned short* __restrict__ cN,
        const int* __restrict__ labels, const float* __restrict__ pos,
        float* __restrict__ partialL, unsigned int* __restrict__ partialC) {
    __shared__ __align__(16) unsigned short As[3][BM * BK];   // 48 KB
    __shared__ __align__(16) unsigned short Bs[3][BN * BK];   // 24 KB

    const int tid  = threadIdx.x;
    const int w    = tid >> 6;        // wave 0..3
    const int lane = tid & 63;
    const int wr   = w >> 1;          // 0..1  M half  (rows wr*128..+127)
    const int wn   = w & 1;           // 0..1  N half  (cols wn*64..+63)
    const int rowBase = blockIdx.y * BM;
    const int colBase = blockIdx.x * BN;

    const int lr = lane & 15;
    const int kq = lane >> 4;         // 16B k-segment 0..3

    // staging: each issue covers 16 rows x 4 segs (lane l -> row l>>2, seg l&3)
    // pre-swizzled global k-seg so LDS can stay linear:
    const int gseg = (lane & 3) ^ ((lane >> 3) & 3);
    const unsigned short* aB0 = fN + (size_t)(rowBase +   0 + w * 16 + (lane >> 2)) * D_DIM + gseg * 8;
    const unsigned short* aB1 = fN + (size_t)(rowBase +  64 + w * 16 + (lane >> 2)) * D_DIM + gseg * 8;
    const unsigned short* aB2 = fN + (size_t)(rowBase + 128 + w * 16 + (lane >> 2)) * D_DIM + gseg * 8;
    const unsigned short* aB3 = fN + (size_t)(rowBase + 192 + w * 16 + (lane >> 2)) * D_DIM + gseg * 8;
    const unsigned short* bB0 = cN + (size_t)(colBase +   0 + w * 16 + (lane >> 2)) * D_DIM + gseg * 8;
    const unsigned short* bB1 = cN + (size_t)(colBase +  64 + w * 16 + (lane >> 2)) * D_DIM + gseg * 8;

#define STAGE(buf, kt)                                                      \
    do {                                                                    \
        const int ko_ = (kt) * BK;                                          \
        gload_lds16(aB0 + ko_, &As[buf][(  0 + w * 16) * BK]);              \
        gload_lds16(aB1 + ko_, &As[buf][( 64 + w * 16) * BK]);              \
        gload_lds16(aB2 + ko_, &As[buf][(128 + w * 16) * BK]);              \
        gload_lds16(aB3 + ko_, &As[buf][(192 + w * 16) * BK]);              \
        gload_lds16(bB0 + ko_, &Bs[buf][(  0 + w * 16) * BK]);              \
        gload_lds16(bB1 + ko_, &Bs[buf][( 64 + w * 16) * BK]);              \
    } while (0)

    f32x4 acc[8][4] = {};

    // prologue: tiles 0 and 1 in flight (12 loads)
    STAGE(0, 0);
    STAGE(1, 1);

    #pragma unroll
    for (int t = 0; t < NKT; ++t) {
        const int b = t % 3;
        // tile t landed (leave tile t+1's 6 loads in flight)
        if (t < NKT - 1) asm volatile("s_waitcnt vmcnt(6)" ::: "memory");
        else             asm volatile("s_waitcnt vmcnt(0)" ::: "memory");
        __builtin_amdgcn_s_barrier();      // all waves' slices landed; all
                                           // reads of buf[(t+2)%3] (tile t-1) done
        if (t + 2 < NKT) STAGE((t + 2) % 3, t + 2);

        // ---- fragments (swizzled read): 12 x ds_read_b128 ----
        bfrag8 af[8], bb[4];
        #pragma unroll
        for (int m = 0; m < 8; ++m)
            af[m] = *(const bfrag8*)&As[b][(wr * 128 + m * 16 + lr) * BK +
                                           ((kq ^ ((lr >> 1) & 3)) * 8)];
        #pragma unroll
        for (int n = 0; n < 4; ++n)
            bb[n] = *(const bfrag8*)&Bs[b][(wn * 64 + n * 16 + lr) * BK +
                                           ((kq ^ ((lr >> 1) & 3)) * 8)];
        asm volatile("s_waitcnt lgkmcnt(0)" ::: "memory");
        __builtin_amdgcn_sched_barrier(0);

        // ---- 32 MFMA (all independent accumulators) ----
        __builtin_amdgcn_s_setprio(1);
        #pragma unroll
        for (int m = 0; m < 8; ++m)
            #pragma unroll
            for (int n = 0; n < 4; ++n)
                acc[m][n] = __builtin_amdgcn_mfma_f32_16x16x32_bf16(
                                af[m], bb[n], acc[m][n], 0, 0, 0);
        __builtin_amdgcn_s_setprio(0);
    }
#undef STAGE

    // ---- epilogue: x = S_ij - pos[i]; mask j != label[i]; softplus; sum ----
    float lsum = 0.0f;
    unsigned cnt = 0;
    #pragma unroll
    for (int m = 0; m < 8; ++m) {
        #pragma unroll
        for (int j = 0; j < 4; ++j) {
            const int gi = rowBase + wr * 128 + m * 16 + kq * 4 + j;
            const float p = pos[gi];
            const int lab = labels[gi];
            #pragma unroll
            for (int n = 0; n < 4; ++n) {
                const int gj = colBase + wn * 64 + n * 16 + lr;
                const float x = acc[m][n][j] - p;
                if (gj != lab) {
                    const float l = __logf(1.0f + __expf(x));   // softplus
                    if (l > 0.0f) { lsum += l; cnt++; }
                }
            }
        }
    }
    #pragma unroll
    for (int off = 32; off; off >>= 1) {
        lsum += __shfl_xor(lsum, off);
        cnt  += __shfl_xor(cnt,  off);
    }
    if (lane == 0) {
        const int bid = blockIdx.y * gridDim.x + blockIdx.x;
        partialL[bid * 4 + w] = lsum;
        partialC[bid * 4 + w] = cnt;
    }
}

// ---------------- finalize: reduce 4096 per-wave partials ----------------
__global__ __launch_bounds__(256) void finalize_kernel(
        const float* __restrict__ partialL, const unsigned int* __restrict__ partialC,
        float* __restrict__ out) {
    __shared__ float    s_sum[4];
    __shared__ unsigned s_cnt[4];
    const int w    = threadIdx.x >> 6;
    const int lane = threadIdx.x & 63;

    float s = 0.0f; unsigned c = 0;
    for (int i = threadIdx.x; i < NPART; i += 256) { s += partialL[i]; c += partialC[i]; }
    #pragma unroll
    for (int off = 32; off; off >>= 1) {
        s += __shfl_xor(s, off);
        c += __shfl_xor(c, off);
    }
    if (lane == 0) { s_sum[w] = s; s_cnt[w] = c; }
    __syncthreads();
    if (threadIdx.x == 0) {
        const float    l = s_sum[0] + s_sum[1] + s_sum[2] + s_sum[3];
        const unsigned n = s_cnt[0] + s_cnt[1] + s_cnt[2] + s_cnt[3];
        out[0] = (n > 0u) ? l / (float)n : l;
    }
}

extern "C" void kernel_launch(void* const* d_in, const int* in_sizes, int n_in,
                              void* d_out, int out_size, void* d_ws, size_t ws_size,
                              hipStream_t stream) {
    const float* features = (const float*)d_in[0];   // [4096, 512]
    const float* centers  = (const float*)d_in[1];   // [8192, 512]
    const int*   labels   = (const int*)d_in[2];     // [4096]
    float* out = (float*)d_out;

    char* ws = (char*)d_ws;
    unsigned short* fN  = (unsigned short*)ws;                        // 4 MB
    unsigned short* cN  = (unsigned short*)(ws + (4u << 20));         // 8 MB
    float*          pos = (float*)(ws + (12u << 20));                 // 16 KB
    float*          partialL = (float*)(ws + (12u << 20) + (1u << 16));            // 16 KB
    unsigned int*   partialC = (unsigned int*)(ws + (12u << 20) + (1u << 16) + (1u << 14)); // 16 KB

    normalize_kernel<<<N_ROWS / 4, 256, 0, stream>>>(features, fN, N_ROWS);
    normalize_kernel<<<C_ROWS / 4, 256, 0, stream>>>(centers,  cN, C_ROWS);
    posdot_kernel<<<N_ROWS / 4, 256, 0, stream>>>(fN, cN, labels, pos);

    dim3 grid(GX, GY);   // 64 x 16 = 1024 blocks, 256 threads
    fused_loss_kernel<<<grid, 256, 0, stream>>>(fN, cN, labels, pos, partialL, partialC);

    finalize_kernel<<<1, 256, 0, stream>>>(partialL, partialC, out);
}

// Round 7
// 74.149 us; speedup vs baseline: 2.2457x; 1.1693x over previous
//
#include <hip/hip_runtime.h>

#define N_ROWS 4096
#define D_DIM  512
#define C_ROWS 8192
#define BM 256
#define BN 256
#define BK 64
#define NKT (D_DIM / BK)        // 8 K-tiles
#define GX (C_ROWS / BN)        // 32
#define GY (N_ROWS / BM)        // 16
#define NBLK (GX * GY)          // 512

typedef __attribute__((ext_vector_type(8))) short bfrag8;   // 8 bf16
typedef __attribute__((ext_vector_type(4))) float f32x4;    // MFMA acc
typedef __attribute__((ext_vector_type(8))) unsigned short ushort8;

#define AS1 __attribute__((address_space(1)))
#define AS3 __attribute__((address_space(3)))

__device__ __forceinline__ void gload_lds16(const void* g, void* l) {
    __builtin_amdgcn_global_load_lds((const AS1 unsigned int*)g,
                                     (AS3 unsigned int*)l, 16, 0, 0);
}

__device__ __forceinline__ unsigned short f2bf(float f) {
    unsigned int u = __float_as_uint(f);
    unsigned int r = (u + 0x7fffu + ((u >> 16) & 1u)) >> 16;   // RNE
    return (unsigned short)r;
}
__device__ __forceinline__ float bf2f(unsigned short h) {
    return __uint_as_float(((unsigned int)h) << 16);
}

// ------------- l2-normalize rows, fp32 -> bf16 (f and c merged) -------------
__global__ __launch_bounds__(256) void normalize_kernel(
        const float* __restrict__ feat, const float* __restrict__ cent,
        unsigned short* __restrict__ fN, unsigned short* __restrict__ cN) {
    const int w    = threadIdx.x >> 6;
    const int lane = threadIdx.x & 63;
    const int row  = blockIdx.x * 4 + w;      // 0 .. 12287

    const float* src = (row < N_ROWS) ? feat + (size_t)row * D_DIM
                                      : cent + (size_t)(row - N_ROWS) * D_DIM;
    unsigned short* dst = (row < N_ROWS) ? fN + (size_t)row * D_DIM
                                         : cN + (size_t)(row - N_ROWS) * D_DIM;

    const float* r = src + lane * 8;
    float4 v0 = *(const float4*)(r);
    float4 v1 = *(const float4*)(r + 4);
    float ss = v0.x*v0.x + v0.y*v0.y + v0.z*v0.z + v0.w*v0.w
             + v1.x*v1.x + v1.y*v1.y + v1.z*v1.z + v1.w*v1.w;
    #pragma unroll
    for (int off = 32; off; off >>= 1) ss += __shfl_xor(ss, off);
    const float nrm = sqrtf(ss);
    const float sc  = 1.0f / fmaxf(nrm, 1e-12f);

    ushort8 pk;
    pk[0] = f2bf(v0.x * sc); pk[1] = f2bf(v0.y * sc);
    pk[2] = f2bf(v0.z * sc); pk[3] = f2bf(v0.w * sc);
    pk[4] = f2bf(v1.x * sc); pk[5] = f2bf(v1.y * sc);
    pk[6] = f2bf(v1.z * sc); pk[7] = f2bf(v1.w * sc);
    *(ushort8*)(dst + lane * 8) = pk;
}

// ---------------- pos_dot[i] = fN[i] . cN[labels[i]] ----------------
__global__ __launch_bounds__(256) void posdot_kernel(
        const unsigned short* __restrict__ fN, const unsigned short* __restrict__ cN,
        const int* __restrict__ labels, float* __restrict__ pos) {
    const int w    = threadIdx.x >> 6;
    const int lane = threadIdx.x & 63;
    const int i    = blockIdx.x * 4 + w;
    const int lab  = labels[i];

    ushort8 a = *(const ushort8*)(fN + (size_t)i   * D_DIM + lane * 8);
    ushort8 b = *(const ushort8*)(cN + (size_t)lab * D_DIM + lane * 8);
    float s = 0.0f;
    #pragma unroll
    for (int t = 0; t < 8; ++t) s += bf2f(a[t]) * bf2f(b[t]);
    #pragma unroll
    for (int off = 32; off; off >>= 1) s += __shfl_xor(s, off);
    if (lane == 0) pos[i] = s;
}

// ---------------- fused GEMM + masked softplus reduction ----------------
// 256x256 tile, BK=64, 8 waves (2M x 4N), 4-phase counted-vmcnt schedule
// (identical to R4's verified kernel). NEW: XCD-stripe block mapping --
// 1-D grid, round-robin dispatch puts id%8 on XCD k; XCD k owns cN columns
// [k*1024, (k+1)*1024) (1 MB, L2-resident); the 4 column-blocks of one
// M-tile are temporally adjacent (c4 inner) so each A-tile is L3-fetched
// once and L2-hit 3 more times. Per-XCD L2 footprint ~3 MB < 4 MB.
__global__ __launch_bounds__(512, 2) void fused_loss_kernel(
        const unsigned short* __restrict__ fN, const unsigned short* __restrict__ cN,
        const int* __restrict__ labels, const float* __restrict__ pos,
        float* __restrict__ partialL, unsigned int* __restrict__ partialC) {
    __shared__ __align__(16) unsigned short As[2][BM * BK];   // 64 KB
    __shared__ __align__(16) unsigned short Bs[2][BN * BK];   // 64 KB

    const int tid  = threadIdx.x;
    const int w    = tid >> 6;        // wave 0..7
    const int lane = tid & 63;
    const int wr   = w >> 2;          // 0..1  (M half)
    const int wn   = w & 3;           // 0..3  (N quarter)

    // XCD-stripe mapping (bijective: 512 = 8 xcd * 16 m * 4 c4)
    const int id  = blockIdx.x;
    const int xcd = id & 7;
    const int loc = id >> 3;          // 0..63
    const int c4  = loc & 3;          // inner: 4 col-blocks of same M adjacent
    const int mt  = loc >> 2;         // 0..15
    const int rowBase = mt * BM;
    const int colBase = (xcd * 4 + c4) * BN;

    const int lr = lane & 15;
    const int kq = lane >> 4;

    // ---- staging geometry ----
    const int rsub = lane >> 3;                 // 0..7
    const int gseg = (lane & 7) ^ rsub;         // pre-swizzled 16B k-seg
    const unsigned short* aBase =
        fN + (size_t)(rowBase + w * 8 + rsub) * D_DIM + gseg * 8;
    const unsigned short* bBase =
        cN + (size_t)(colBase + (w >> 2) * 64 + (w & 3) * 8 + rsub) * D_DIM + gseg * 8;

#define STAGE_A(buf, kt, mh, i)                                                  \
    gload_lds16(aBase + ((size_t)((mh) * 64 + (i) * 128) * D_DIM + (kt) * BK),   \
                &As[buf][((mh) * 64 + (i) * 128 + w * 8) * BK])
#define STAGE_B(buf, kt, nh, i)                                                  \
    gload_lds16(bBase + ((size_t)((i) * 128 + (nh) * 32) * D_DIM + (kt) * BK),   \
                &Bs[buf][((i) * 128 + (nh) * 32 + (w >> 2) * 64 + (w & 3) * 8) * BK])
#define CHUNK_A(buf, kt, mh) do { STAGE_A(buf, kt, mh, 0); STAGE_A(buf, kt, mh, 1); } while (0)
#define CHUNK_B(buf, kt, nh) do { STAGE_B(buf, kt, nh, 0); STAGE_B(buf, kt, nh, 1); } while (0)

#define READ_A(dst, b, m, kk)                                                    \
    dst = *(const bfrag8*)&As[b][(wr * 128 + (m) * 16 + lr) * BK +               \
                                 ((((kk) * 4 + kq) ^ (lr & 7)) * 8)]
#define READ_B(dst, b, n, kk)                                                    \
    dst = *(const bfrag8*)&Bs[b][(wn * 64 + (n) * 16 + lr) * BK +                \
                                 ((((kk) * 4 + kq) ^ (lr & 7)) * 8)]

    f32x4 acc[8][4] = {};
    bfrag8 af[4][2];        // current M-half A frags [m4][kk]
    bfrag8 bb[2][2][2];     // B frags [nh][n2][kk]

    // prologue: stage tile 0 in steady-state chunk order A0,B0,B1,A1
    CHUNK_A(0, 0, 0); CHUNK_B(0, 0, 0); CHUNK_B(0, 0, 1); CHUNK_A(0, 0, 1);

    #pragma unroll
    for (int t = 0; t < NKT; ++t) {
        const int b  = t & 1;
        const int nb = b ^ 1;
        const bool pf = (t + 1 < NKT);

        // ---------- P0: quadrant (mh=0, nh=0); needs chunks A0,B0 ----------
        asm volatile("s_waitcnt vmcnt(4)" ::: "memory");
        __builtin_amdgcn_s_barrier();
        #pragma unroll
        for (int m4 = 0; m4 < 4; ++m4) { READ_A(af[m4][0], b, m4, 0); READ_A(af[m4][1], b, m4, 1); }
        #pragma unroll
        for (int n2 = 0; n2 < 2; ++n2) { READ_B(bb[0][n2][0], b, n2, 0); READ_B(bb[0][n2][1], b, n2, 1); }
        if (pf) CHUNK_A(nb, t + 1, 0);
        asm volatile("s_waitcnt lgkmcnt(0)" ::: "memory");
        __builtin_amdgcn_sched_barrier(0);
        __builtin_amdgcn_s_setprio(1);
        #pragma unroll
        for (int kk = 0; kk < 2; ++kk)
            #pragma unroll
            for (int m4 = 0; m4 < 4; ++m4)
                #pragma unroll
                for (int n2 = 0; n2 < 2; ++n2)
                    acc[m4][n2] = __builtin_amdgcn_mfma_f32_16x16x32_bf16(
                                      af[m4][kk], bb[0][n2][kk], acc[m4][n2], 0, 0, 0);
        __builtin_amdgcn_s_setprio(0);

        // ---------- P1: quadrant (mh=0, nh=1); needs chunk B1 ----------
        if (pf) asm volatile("s_waitcnt vmcnt(4)" ::: "memory");
        else    asm volatile("s_waitcnt vmcnt(2)" ::: "memory");
        __builtin_amdgcn_s_barrier();
        #pragma unroll
        for (int n2 = 0; n2 < 2; ++n2) { READ_B(bb[1][n2][0], b, 2 + n2, 0); READ_B(bb[1][n2][1], b, 2 + n2, 1); }
        if (pf) CHUNK_B(nb, t + 1, 0);
        asm volatile("s_waitcnt lgkmcnt(0)" ::: "memory");
        __builtin_amdgcn_sched_barrier(0);
        __builtin_amdgcn_s_setprio(1);
        #pragma unroll
        for (int kk = 0; kk < 2; ++kk)
            #pragma unroll
            for (int m4 = 0; m4 < 4; ++m4)
                #pragma unroll
                for (int n2 = 0; n2 < 2; ++n2)
                    acc[m4][2 + n2] = __builtin_amdgcn_mfma_f32_16x16x32_bf16(
                                          af[m4][kk], bb[1][n2][kk], acc[m4][2 + n2], 0, 0, 0);
        __builtin_amdgcn_s_setprio(0);

        // ---------- P2: quadrant (mh=1, nh=0); needs chunk A1 ----------
        if (pf) asm volatile("s_waitcnt vmcnt(4)" ::: "memory");
        else    asm volatile("s_waitcnt vmcnt(0)" ::: "memory");
        __builtin_amdgcn_s_barrier();
        #pragma unroll
        for (int m4 = 0; m4 < 4; ++m4) { READ_A(af[m4][0], b, 4 + m4, 0); READ_A(af[m4][1], b, 4 + m4, 1); }
        if (pf) CHUNK_B(nb, t + 1, 1);
        asm volatile("s_waitcnt lgkmcnt(0)" ::: "memory");
        __builtin_amdgcn_sched_barrier(0);
        __builtin_amdgcn_s_setprio(1);
        #pragma unroll
        for (int kk = 0; kk < 2; ++kk)
            #pragma unroll
            for (int m4 = 0; m4 < 4; ++m4)
                #pragma unroll
                for (int n2 = 0; n2 < 2; ++n2)
                    acc[4 + m4][n2] = __builtin_amdgcn_mfma_f32_16x16x32_bf16(
                                          af[m4][kk], bb[0][n2][kk], acc[4 + m4][n2], 0, 0, 0);
        __builtin_amdgcn_s_setprio(0);

        // ---------- P3: quadrant (mh=1, nh=1); no new reads, no barrier ----------
        if (pf) CHUNK_A(nb, t + 1, 1);
        __builtin_amdgcn_s_setprio(1);
        #pragma unroll
        for (int kk = 0; kk < 2; ++kk)
            #pragma unroll
            for (int m4 = 0; m4 < 4; ++m4)
                #pragma unroll
                for (int n2 = 0; n2 < 2; ++n2)
                    acc[4 + m4][2 + n2] = __builtin_amdgcn_mfma_f32_16x16x32_bf16(
                                              af[m4][kk], bb[1][n2][kk], acc[4 + m4][2 + n2], 0, 0, 0);
        __builtin_amdgcn_s_setprio(0);
    }

#undef STAGE_A
#undef STAGE_B
#undef CHUNK_A
#undef CHUNK_B
#undef READ_A
#undef READ_B

    // ---- epilogue: x = S_ij - pos[i]; mask j != label[i]; softplus; sum ----
    float lsum = 0.0f;
    unsigned cnt = 0;
    #pragma unroll
    for (int m = 0; m < 8; ++m) {
        #pragma unroll
        for (int j = 0; j < 4; ++j) {
            const int gi = rowBase + wr * 128 + m * 16 + kq * 4 + j;
            const float p = pos[gi];
            const int lab = labels[gi];
            #pragma unroll
            for (int n = 0; n < 4; ++n) {
                const int gj = colBase + wn * 64 + n * 16 + lr;
                const float x = acc[m][n][j] - p;
                if (gj != lab) {
                    const float l = __logf(1.0f + __expf(x));   // softplus
                    if (l > 0.0f) { lsum += l; cnt++; }
                }
            }
        }
    }
    #pragma unroll
    for (int off = 32; off; off >>= 1) {
        lsum += __shfl_xor(lsum, off);
        cnt  += __shfl_xor(cnt,  off);
    }

    __syncthreads();                        // safe to reuse LDS
    float*    s_sum = (float*)&As[0][0];
    unsigned* s_cnt = (unsigned*)&As[0][64];
    if (lane == 0) { s_sum[w] = lsum; s_cnt[w] = cnt; }
    __syncthreads();
    if (tid == 0) {
        float    L = 0.0f;
        unsigned C = 0;
        #pragma unroll
        for (int i = 0; i < 8; ++i) { L += s_sum[i]; C += s_cnt[i]; }
        partialL[id] = L;
        partialC[id] = C;
    }
}

// ---------------- finalize: reduce 512 per-block partials ----------------
__global__ __launch_bounds__(256) void finalize_kernel(
        const float* __restrict__ partialL, const unsigned int* __restrict__ partialC,
        float* __restrict__ out) {
    __shared__ float    s_sum[4];
    __shared__ unsigned s_cnt[4];
    const int w    = threadIdx.x >> 6;
    const int lane = threadIdx.x & 63;

    float s = 0.0f; unsigned c = 0;
    for (int i = threadIdx.x; i < NBLK; i += 256) { s += partialL[i]; c += partialC[i]; }
    #pragma unroll
    for (int off = 32; off; off >>= 1) {
        s += __shfl_xor(s, off);
        c += __shfl_xor(c, off);
    }
    if (lane == 0) { s_sum[w] = s; s_cnt[w] = c; }
    __syncthreads();
    if (threadIdx.x == 0) {
        const float    l = s_sum[0] + s_sum[1] + s_sum[2] + s_sum[3];
        const unsigned n = s_cnt[0] + s_cnt[1] + s_cnt[2] + s_cnt[3];
        out[0] = (n > 0u) ? l / (float)n : l;
    }
}

extern "C" void kernel_launch(void* const* d_in, const int* in_sizes, int n_in,
                              void* d_out, int out_size, void* d_ws, size_t ws_size,
                              hipStream_t stream) {
    const float* features = (const float*)d_in[0];   // [4096, 512]
    const float* centers  = (const float*)d_in[1];   // [8192, 512]
    const int*   labels   = (const int*)d_in[2];     // [4096]
    float* out = (float*)d_out;

    char* ws = (char*)d_ws;
    unsigned short* fN  = (unsigned short*)ws;                        // 4 MB
    unsigned short* cN  = (unsigned short*)(ws + (4u << 20));         // 8 MB
    float*          pos = (float*)(ws + (12u << 20));                 // 16 KB
    float*          partialL = (float*)(ws + (12u << 20) + (1u << 16));
    unsigned int*   partialC = (unsigned int*)(ws + (12u << 20) + (1u << 16) + (1u << 13));

    normalize_kernel<<<(N_ROWS + C_ROWS) / 4, 256, 0, stream>>>(features, centers, fN, cN);
    posdot_kernel<<<N_ROWS / 4, 256, 0, stream>>>(fN, cN, labels, pos);

    fused_loss_kernel<<<NBLK, 512, 0, stream>>>(fN, cN, labels, pos, partialL, partialC);

    finalize_kernel<<<1, 256, 0, stream>>>(partialL, partialC, out);
}

// Round 9
// 53.496 us; speedup vs baseline: 3.1127x; 1.3861x over previous
//
#include <hip/hip_runtime.h>

#define N_ROWS 4096
#define D_DIM  512
#define ROWB   512              // bytes per fp8 row
#define C_ROWS 8192
#define BM 256
#define BN 128
#define BKB 64                  // K-tile bytes = 64 fp8 elems
#define NKT 8                   // 512 / 64
#define GXf (C_ROWS / BN)       // 64
#define GYf (N_ROWS / BM)       // 16
#define NBLK (GXf * GYf)        // 1024

typedef __attribute__((ext_vector_type(4))) float f32x4;
typedef __attribute__((ext_vector_type(2))) long  i64x2;    // one ds_read_b128

#define AS1 __attribute__((address_space(1)))
#define AS3 __attribute__((address_space(3)))

__device__ __forceinline__ void gload_lds16(const void* g, void* l) {
    __builtin_amdgcn_global_load_lds((const AS1 unsigned int*)g,
                                     (AS3 unsigned int*)l, 16, 0, 0);
}

// ---------------- l2-normalize rows, fp32 -> fp8 e4m3, k-permuted ----------
// k-permutation (within each 64-elem block): dest byte q*16+h*8+b holds
// orig k = q*8 + h*32 + b.  Same permutation for f and c => dots invariant.
__global__ __launch_bounds__(256) void normalize_kernel(
        const float* __restrict__ feat, const float* __restrict__ cent,
        unsigned char* __restrict__ fN, unsigned char* __restrict__ cN) {
    const int w    = threadIdx.x >> 6;
    const int lane = threadIdx.x & 63;
    const int row  = blockIdx.x * 4 + w;      // 0 .. 12287

    const float* src = (row < N_ROWS) ? feat + (size_t)row * D_DIM
                                      : cent + (size_t)(row - N_ROWS) * D_DIM;
    unsigned char* dst = (row < N_ROWS) ? fN + (size_t)row * ROWB
                                        : cN + (size_t)(row - N_ROWS) * ROWB;

    const float* r = src + lane * 8;
    float4 v0 = *(const float4*)(r);
    float4 v1 = *(const float4*)(r + 4);
    float ss = v0.x*v0.x + v0.y*v0.y + v0.z*v0.z + v0.w*v0.w
             + v1.x*v1.x + v1.y*v1.y + v1.z*v1.z + v1.w*v1.w;
    #pragma unroll
    for (int off = 32; off; off >>= 1) ss += __shfl_xor(ss, off);
    const float sc = 1.0f / fmaxf(sqrtf(ss), 1e-12f);

    int p0 = __builtin_amdgcn_cvt_pk_fp8_f32(v0.x * sc, v0.y * sc, 0, false);
    p0     = __builtin_amdgcn_cvt_pk_fp8_f32(v0.z * sc, v0.w * sc, p0, true);
    int p1 = __builtin_amdgcn_cvt_pk_fp8_f32(v1.x * sc, v1.y * sc, 0, false);
    p1     = __builtin_amdgcn_cvt_pk_fp8_f32(v1.z * sc, v1.w * sc, p1, true);

    // lane handles orig k = lane*8..+8 -> kb=lane>>3, q=lane&3, h=(lane>>2)&1
    const int db = ((lane >> 3) << 6) + ((lane & 3) << 4) + (((lane >> 2) & 1) << 3);
    uint2 o; o.x = (unsigned)p0; o.y = (unsigned)p1;
    *(uint2*)(dst + db) = o;
}

// ---------------- pos_dot[i] = fN[i] . cN[labels[i]]  (fp8 inputs) ---------
__global__ __launch_bounds__(256) void posdot_kernel(
        const unsigned char* __restrict__ fN, const unsigned char* __restrict__ cN,
        const int* __restrict__ labels, float* __restrict__ pos) {
    const int w    = threadIdx.x >> 6;
    const int lane = threadIdx.x & 63;
    const int i    = blockIdx.x * 4 + w;
    const int lab  = labels[i];

    const uint2 a = *(const uint2*)(fN + (size_t)i   * ROWB + lane * 8);
    const uint2 b = *(const uint2*)(cN + (size_t)lab * ROWB + lane * 8);
    float s = 0.0f;
    // byte-select operand must be a LITERAL constant -> fully expanded
    s += __builtin_amdgcn_cvt_f32_fp8((int)a.x, 0) * __builtin_amdgcn_cvt_f32_fp8((int)b.x, 0);
    s += __builtin_amdgcn_cvt_f32_fp8((int)a.x, 1) * __builtin_amdgcn_cvt_f32_fp8((int)b.x, 1);
    s += __builtin_amdgcn_cvt_f32_fp8((int)a.x, 2) * __builtin_amdgcn_cvt_f32_fp8((int)b.x, 2);
    s += __builtin_amdgcn_cvt_f32_fp8((int)a.x, 3) * __builtin_amdgcn_cvt_f32_fp8((int)b.x, 3);
    s += __builtin_amdgcn_cvt_f32_fp8((int)a.y, 0) * __builtin_amdgcn_cvt_f32_fp8((int)b.y, 0);
    s += __builtin_amdgcn_cvt_f32_fp8((int)a.y, 1) * __builtin_amdgcn_cvt_f32_fp8((int)b.y, 1);
    s += __builtin_amdgcn_cvt_f32_fp8((int)a.y, 2) * __builtin_amdgcn_cvt_f32_fp8((int)b.y, 2);
    s += __builtin_amdgcn_cvt_f32_fp8((int)a.y, 3) * __builtin_amdgcn_cvt_f32_fp8((int)b.y, 3);
    #pragma unroll
    for (int off = 32; off; off >>= 1) s += __shfl_xor(s, off);
    if (lane == 0) pos[i] = s;
}

// ---------------- fused fp8 GEMM + masked softplus reduction ----------------
// 256x128 tile, BK=64B, 8 waves (4M x 2N, wave tile 64x64), double-buffered,
// R3-style loop (2 barriers/K-tile, counted vmcnt(3), stage after mid-bar).
// LDS seg swizzle: seg' = seg ^ ((r ^ (r>>2)) & 3)  => <=2-way banks (free).
// __launch_bounds__(512,4): <=128 VGPR -> 16 waves/CU = 2 independent
// blocks/CU (stall overlap; R3 evidence this class reaches delivery ceiling).
__global__ __launch_bounds__(512, 4) void fused_loss_kernel(
        const unsigned char* __restrict__ fN, const unsigned char* __restrict__ cN,
        const int* __restrict__ labels, const float* __restrict__ pos,
        float* __restrict__ partialL, unsigned int* __restrict__ partialC) {
    __shared__ __align__(16) unsigned char As[2][BM * BKB];   // 32 KB
    __shared__ __align__(16) unsigned char Bs[2][BN * BKB];   // 16 KB

    const int tid  = threadIdx.x;
    const int w    = tid >> 6;        // wave 0..7
    const int lane = tid & 63;
    const int wm   = w >> 1;          // 0..3  (M quarter: rows wm*64..+63)
    const int wn   = w & 1;           // 0..1  (N half:   cols wn*64..+63)
    const int rowBase = blockIdx.y * BM;
    const int colBase = blockIdx.x * BN;

    const int lr = lane & 15;
    const int kq = lane >> 4;         // 0..3 = 16B seg (both kk halves)

    // staging: chunk = 16 rows x 64B; lane l -> row l>>2, LDS seg l&3,
    // fetching pre-swizzled global seg (l&3)^f(l>>2), f(x)=(x^(x>>2))&3
    const int gseg = ((lane & 3) ^ ((lane >> 2) & 3) ^ ((lane >> 4) & 3));
    const unsigned char* aG = fN + (size_t)(rowBase + w * 32 + (lane >> 2)) * ROWB + gseg * 16;
    const unsigned char* bG = cN + (size_t)(colBase + w * 16 + (lane >> 2)) * ROWB + gseg * 16;

#define STAGE(buf, t)                                                        \
    do {                                                                     \
        gload_lds16(aG + (t) * BKB,             &As[buf][(w * 32) * BKB]);   \
        gload_lds16(aG + (t) * BKB + 16 * ROWB, &As[buf][(w * 32 + 16) * BKB]); \
        gload_lds16(bG + (t) * BKB,             &Bs[buf][(w * 16) * BKB]);   \
    } while (0)

    // read: lane wants global seg kq at row (16-aligned base + lr):
    // LDS seg = kq ^ f(lr);   b128 -> [kk=0 | kk=1] halves
    const int segrd = (lane ^ (lane >> 2) ^ (lane >> 4)) & 3;
    const int loff  = lr * BKB + segrd * 16;     // per-lane offset in tile

    f32x4 acc[4][4] = {};

    // prologue: tiles 0,1 in flight (6 loads/wave)
    STAGE(0, 0);
    STAGE(1, 1);
    asm volatile("s_waitcnt vmcnt(3)" ::: "memory");
    __builtin_amdgcn_s_barrier();

    #pragma unroll
    for (int t = 0; t < NKT; ++t) {
        const int cur = t & 1;

        i64x2 af[4], bb[4];
        #pragma unroll
        for (int m = 0; m < 4; ++m)
            af[m] = *(const i64x2*)&As[cur][(wm * 64 + m * 16) * BKB + loff];
        #pragma unroll
        for (int n = 0; n < 4; ++n)
            bb[n] = *(const i64x2*)&Bs[cur][(wn * 64 + n * 16) * BKB + loff];
        asm volatile("s_waitcnt lgkmcnt(0)" ::: "memory");
        __builtin_amdgcn_sched_barrier(0);
        __builtin_amdgcn_s_barrier();            // all waves done with buf[cur]

        if (t + 2 < NKT) STAGE(cur, t + 2);      // overwrite freed buffer

        #pragma unroll
        for (int kk = 0; kk < 2; ++kk)
            #pragma unroll
            for (int m = 0; m < 4; ++m)
                #pragma unroll
                for (int n = 0; n < 4; ++n)
                    acc[m][n] = __builtin_amdgcn_mfma_f32_16x16x32_fp8_fp8(
                                    af[m][kk], bb[n][kk], acc[m][n], 0, 0, 0);

        if (t < NKT - 1) {
            if (t < NKT - 2) asm volatile("s_waitcnt vmcnt(3)" ::: "memory");
            else             asm volatile("s_waitcnt vmcnt(0)" ::: "memory");
            __builtin_amdgcn_s_barrier();        // next tile landed chip-wide
        }
    }
#undef STAGE

    // ---- epilogue: x = S_ij - pos[i]; mask j != label[i]; softplus; sum ----
    float lsum = 0.0f;
    unsigned cnt = 0;
    #pragma unroll
    for (int m = 0; m < 4; ++m) {
        #pragma unroll
        for (int j = 0; j < 4; ++j) {
            const int gi = rowBase + wm * 64 + m * 16 + kq * 4 + j;
            const float p = pos[gi];
            const int lab = labels[gi];
            #pragma unroll
            for (int n = 0; n < 4; ++n) {
                const int gj = colBase + wn * 64 + n * 16 + lr;
                const float x = acc[m][n][j] - p;
                if (gj != lab) {
                    const float l = __logf(1.0f + __expf(x));   // softplus
                    if (l > 0.0f) { lsum += l; cnt++; }
                }
            }
        }
    }
    #pragma unroll
    for (int off = 32; off; off >>= 1) {
        lsum += __shfl_xor(lsum, off);
        cnt  += __shfl_xor(cnt,  off);
    }

    __syncthreads();                        // safe to reuse LDS
    float*    s_sum = (float*)&As[0][0];
    unsigned* s_cnt = (unsigned*)&As[0][64];
    if (lane == 0) { s_sum[w] = lsum; s_cnt[w] = cnt; }
    __syncthreads();
    if (tid == 0) {
        float    L = 0.0f;
        unsigned C = 0;
        #pragma unroll
        for (int i = 0; i < 8; ++i) { L += s_sum[i]; C += s_cnt[i]; }
        const int id = blockIdx.y * gridDim.x + blockIdx.x;
        partialL[id] = L;
        partialC[id] = C;
    }
}

// ---------------- finalize: reduce 1024 per-block partials ----------------
__global__ __launch_bounds__(256) void finalize_kernel(
        const float* __restrict__ partialL, const unsigned int* __restrict__ partialC,
        float* __restrict__ out) {
    __shared__ float    s_sum[4];
    __shared__ unsigned s_cnt[4];
    const int w    = threadIdx.x >> 6;
    const int lane = threadIdx.x & 63;

    float s = 0.0f; unsigned c = 0;
    for (int i = threadIdx.x; i < NBLK; i += 256) { s += partialL[i]; c += partialC[i]; }
    #pragma unroll
    for (int off = 32; off; off >>= 1) {
        s += __shfl_xor(s, off);
        c += __shfl_xor(c, off);
    }
    if (lane == 0) { s_sum[w] = s; s_cnt[w] = c; }
    __syncthreads();
    if (threadIdx.x == 0) {
        const float    l = s_sum[0] + s_sum[1] + s_sum[2] + s_sum[3];
        const unsigned n = s_cnt[0] + s_cnt[1] + s_cnt[2] + s_cnt[3];
        out[0] = (n > 0u) ? l / (float)n : l;
    }
}

extern "C" void kernel_launch(void* const* d_in, const int* in_sizes, int n_in,
                              void* d_out, int out_size, void* d_ws, size_t ws_size,
                              hipStream_t stream) {
    const float* features = (const float*)d_in[0];   // [4096, 512]
    const float* centers  = (const float*)d_in[1];   // [8192, 512]
    const int*   labels   = (const int*)d_in[2];     // [4096]
    float* out = (float*)d_out;

    char* ws = (char*)d_ws;
    unsigned char* fN  = (unsigned char*)ws;                          // 2 MB
    unsigned char* cN  = (unsigned char*)(ws + (2u << 20));           // 4 MB
    float*         pos = (float*)(ws + (6u << 20));                   // 16 KB
    float*         partialL = (float*)(ws + (6u << 20) + (1u << 16));           // 4 KB
    unsigned int*  partialC = (unsigned int*)(ws + (6u << 20) + (1u << 16) + (1u << 14));

    normalize_kernel<<<(N_ROWS + C_ROWS) / 4, 256, 0, stream>>>(features, centers, fN, cN);
    posdot_kernel<<<N_ROWS / 4, 256, 0, stream>>>(fN, cN, labels, pos);

    dim3 grid(GXf, GYf);   // 64 x 16 = 1024 blocks, 512 threads
    fused_loss_kernel<<<grid, 512, 0, stream>>>(fN, cN, labels, pos, partialL, partialC);

    finalize_kernel<<<1, 256, 0, stream>>>(partialL, partialC, out);
}